// Round 1
// baseline (823.741 us; speedup 1.0000x reference)
//
#include <hip/hip_runtime.h>
#include <hip/hip_bf16.h>

typedef __hip_bfloat16 hbf16;
typedef __bf16 bf16x8 __attribute__((ext_vector_type(8)));
typedef float f32x4 __attribute__((ext_vector_type(4)));

#define MFMA16(a, b, c) __builtin_amdgcn_mfma_f32_16x16x32_bf16((a), (b), (c), 0, 0, 0)

// async global->LDS, 16B per lane. LDS dest = wave-uniform base + lane*16.
#define ASYNC16(ldsaddr, gaddr)                                                        \
  __builtin_amdgcn_global_load_lds(                                                    \
      (__attribute__((address_space(1))) void*)(void*)(gaddr),                         \
      (__attribute__((address_space(3))) void*)(ldsaddr), 16, 0, 0)

// ---------------------------------------------------------------- quantization
__global__ void init_gmax_kernel(unsigned int* g) { g[threadIdx.x] = 0u; }

// one block per (group, rowsplit); 64 groups of 64 cols; all matrices have 4096 cols
__global__ void quant_max_kernel(const float* __restrict__ W, unsigned int* __restrict__ gmax,
                                 int slotBase, int rowsPerSplit) {
  const int tid = threadIdx.x;
  const int group = blockIdx.x & 63;
  const int split = blockIdx.x >> 6;
  const int c4 = (tid & 15) * 4;
  const int rs = tid >> 4;  // 0..15
  const float* base = W + (size_t)(split * rowsPerSplit) * 4096 + group * 64 + c4;
  float m = 0.f;
  for (int r = rs; r < rowsPerSplit; r += 16) {
    float4 v = *(const float4*)(base + (size_t)r * 4096);
    m = fmaxf(m, fmaxf(fmaxf(fabsf(v.x), fabsf(v.y)), fmaxf(fabsf(v.z), fabsf(v.w))));
  }
  for (int d = 1; d < 64; d <<= 1) m = fmaxf(m, __shfl_xor(m, d, 64));
  __shared__ float wm_[4];
  if ((tid & 63) == 0) wm_[tid >> 6] = m;
  __syncthreads();
  if (tid == 0) {
    m = fmaxf(fmaxf(wm_[0], wm_[1]), fmaxf(wm_[2], wm_[3]));
    atomicMax(gmax + slotBase + group, __float_as_uint(m));
  }
}

// w_q = trunc(w * 2^(7-gex)) * 2^(gex-7), exact in bf16
__global__ void quant_apply_kernel(const float* __restrict__ W, hbf16* __restrict__ Wq,
                                   const unsigned int* __restrict__ gmax, int slotBase, int n4) {
  const int stride = gridDim.x * 256;
  for (int idx = blockIdx.x * 256 + threadIdx.x; idx < n4; idx += stride) {
    int col4 = idx & 1023;     // 1024 float4 per 4096-col row
    int group = col4 >> 4;     // 16 float4 per 64-col group
    unsigned int mb = gmax[slotBase + group];
    int gex = (int)((mb >> 23) & 255) - 127;
    float s = __uint_as_float((unsigned)(134 - gex) << 23);    // 2^(7-gex)
    float inv = __uint_as_float((unsigned)(120 + gex) << 23);  // 2^(gex-7)
    float4 w = *(const float4*)(W + (size_t)idx * 4);
    hbf16 t[4];
    t[0] = __float2bfloat16(truncf(w.x * s) * inv);
    t[1] = __float2bfloat16(truncf(w.y * s) * inv);
    t[2] = __float2bfloat16(truncf(w.z * s) * inv);
    t[3] = __float2bfloat16(truncf(w.w * s) * inv);
    *(uint2*)(Wq + (size_t)idx * 4) = *(uint2*)t;
  }
}

__global__ void cvt_bf16_kernel(const float* __restrict__ X, hbf16* __restrict__ Y, int n4) {
  const int stride = gridDim.x * 256;
  for (int idx = blockIdx.x * 256 + threadIdx.x; idx < n4; idx += stride) {
    float4 v = *(const float4*)(X + (size_t)idx * 4);
    hbf16 t[4] = {__float2bfloat16(v.x), __float2bfloat16(v.y),
                  __float2bfloat16(v.z), __float2bfloat16(v.w)};
    *(uint2*)(Y + (size_t)idx * 4) = *(uint2*)t;
  }
}

// -------------------------------------------------------------------- RoPE
// one thread per (even,odd) pair. shift: log2(pairs per row).
__global__ void rope_kernel(const float* __restrict__ In, const float* __restrict__ Cs,
                            const float* __restrict__ Sn, hbf16* __restrict__ Out,
                            int shift, int rowStride) {
  int i = blockIdx.x * 256 + threadIdx.x;
  int ppr = 1 << shift;
  if (i >= 2048 * ppr) return;
  int s = i >> shift;
  int p = i & (ppr - 1);
  int t = p & 63;
  float2 q = *(const float2*)(In + (size_t)s * rowStride + p * 2);
  float c = Cs[s * 64 + t], sn = Sn[s * 64 + t];
  hbf16 o[2] = {__float2bfloat16(q.x * c - q.y * sn), __float2bfloat16(q.x * sn + q.y * c)};
  *(unsigned int*)(Out + (size_t)s * ppr * 2 + p * 2) = *(unsigned int*)o;
}

// V [s][1024+g*128+d] (f32) -> Vt [g][d][s] (bf16)
__global__ void transpose_v_kernel(const float* __restrict__ KV, hbf16* __restrict__ Vt) {
  __shared__ float tile[64][65];
  const int g = blockIdx.x, sb = blockIdx.y, db = blockIdx.z;
  const int tid = threadIdx.x;
  const int c = tid & 63;
  for (int r = tid >> 6; r < 64; r += 4)
    tile[r][c] = KV[(size_t)(sb * 64 + r) * 2048 + 1024 + g * 128 + db * 64 + c];
  __syncthreads();
  for (int r = tid >> 6; r < 64; r += 4)
    Vt[(size_t)g * 262144 + (size_t)(db * 64 + r) * 2048 + sb * 64 + c] =
        __float2bfloat16(tile[c][r]);
}

// ------------------------------------------------------------------ GEMM C=A*Bt^T
// A [2048][4096] bf16 row-major, Bt [N][4096] bf16 row-major, C [2048][N] f32.
__global__ __launch_bounds__(256) void gemm_bt_kernel(const hbf16* __restrict__ A,
                                                      const hbf16* __restrict__ Bt,
                                                      float* __restrict__ C, int N) {
  constexpr int K = 4096;
  __shared__ __align__(16) hbf16 sA[128 * 64];
  __shared__ __align__(16) hbf16 sB[128 * 64];
  const int tid = threadIdx.x;
  const int wave = tid >> 6, lane = tid & 63;
  const int l15 = lane & 15, quad = lane >> 4;
  const int bm = blockIdx.x, bn = blockIdx.y;
  const int wm = (wave >> 1) * 64, wn = (wave & 1) * 64;

  const char* Ab = (const char*)(A + (size_t)bm * 128 * K);
  const char* Bb = (const char*)(Bt + (size_t)bn * 128 * K);
  char* sAb = (char*)sA;
  char* sBb = (char*)sB;

  f32x4 acc[4][4];
#pragma unroll
  for (int i = 0; i < 4; ++i)
#pragma unroll
    for (int n = 0; n < 4; ++n) acc[i][n] = (f32x4){0.f, 0.f, 0.f, 0.f};

  for (int kk = 0; kk < K; kk += 64) {
#pragma unroll
    for (int r = 0; r < 4; ++r) {
      int f = r * 4096 + tid * 16;
      int row = f >> 7, cb = f & 127;
      ASYNC16(sAb + f, Ab + (size_t)row * (K * 2) + kk * 2 + cb);
      ASYNC16(sBb + f, Bb + (size_t)row * (K * 2) + kk * 2 + cb);
    }
    __syncthreads();
#pragma unroll
    for (int kc = 0; kc < 2; ++kc) {
      bf16x8 af[4], bg[4];
#pragma unroll
      for (int i = 0; i < 4; ++i)
        af[i] = *(const bf16x8*)(sAb + ((wm + i * 16 + l15) * 64 + kc * 32 + quad * 8) * 2);
#pragma unroll
      for (int n = 0; n < 4; ++n)
        bg[n] = *(const bf16x8*)(sBb + ((wn + n * 16 + l15) * 64 + kc * 32 + quad * 8) * 2);
#pragma unroll
      for (int i = 0; i < 4; ++i)
#pragma unroll
        for (int n = 0; n < 4; ++n) acc[i][n] = MFMA16(af[i], bg[n], acc[i][n]);
    }
    __syncthreads();
  }
#pragma unroll
  for (int i = 0; i < 4; ++i) {
    int row = bm * 128 + wm + i * 16 + quad * 4;
#pragma unroll
    for (int n = 0; n < 4; ++n) {
      float* cp = C + (size_t)row * N + bn * 128 + wn + n * 16 + l15;
#pragma unroll
      for (int r = 0; r < 4; ++r) cp[(size_t)r * N] = acc[i][n][r];
    }
  }
}

// ------------------------------------------------------------- flash attention
// Q [2048][4096] bf16 (col=h*128+d), Kr [2048][1024] bf16 (col=g*128+d),
// Vt [8][128][2048] bf16, O [2048][4096] bf16.
__global__ __launch_bounds__(256) void attn_kernel(const hbf16* __restrict__ Q,
                                                   const hbf16* __restrict__ Kr,
                                                   const hbf16* __restrict__ Vt,
                                                   hbf16* __restrict__ O) {
  __shared__ __align__(16) hbf16 sK[64 * 128];   // [key][d]
  __shared__ __align__(16) hbf16 sV[128 * 64];   // [d][key]
  __shared__ __align__(16) hbf16 sP[4][16 * 72]; // per-wave P, padded stride 72
  const int tid = threadIdx.x;
  const int wave = tid >> 6, lane = tid & 63;
  const int l15 = lane & 15, quad = lane >> 4;
  const int h = blockIdx.x >> 5;
  const int qb = 31 - (blockIdx.x & 31);  // longest blocks first
  const int g = h >> 2;
  const int qrow0 = qb * 64 + wave * 16;

  bf16x8 qf[4];
  {
    const hbf16* qp = Q + (size_t)(qrow0 + l15) * 4096 + h * 128 + quad * 8;
#pragma unroll
    for (int kc = 0; kc < 4; ++kc) qf[kc] = *(const bf16x8*)(qp + kc * 32);
  }
  f32x4 of[8];
#pragma unroll
  for (int nf = 0; nf < 8; ++nf) of[nf] = (f32x4){0.f, 0.f, 0.f, 0.f};
  float mrow[4] = {-1e30f, -1e30f, -1e30f, -1e30f};
  float lrow[4] = {0.f, 0.f, 0.f, 0.f};

  const char* Kb = (const char*)Kr + (size_t)g * 256;     // + s*2048 + d*2
  const char* Vb = (const char*)Vt + (size_t)g * 524288;  // + d*4096 + s*2
  char* sKb = (char*)sK;
  char* sVb = (char*)sV;
  const float kSc = 0.12753139668280277f;  // (1/sqrt(128)) * log2(e)

  const int nkb = qb + 1;
  for (int kb = 0; kb < nkb; ++kb) {
#pragma unroll
    for (int r = 0; r < 4; ++r) {
      int f = r * 4096 + tid * 16;
      {
        int row = f >> 8, cb = f & 255;  // K: 64 keys x 256B
        ASYNC16(sKb + f, Kb + (size_t)(kb * 64 + row) * 2048 + cb);
      }
      {
        int row = f >> 7, cb = f & 127;  // Vt: 128 d x 128B
        ASYNC16(sVb + f, Vb + (size_t)row * 4096 + kb * 128 + cb);
      }
    }
    __syncthreads();

    f32x4 sacc[4];
#pragma unroll
    for (int n = 0; n < 4; ++n) sacc[n] = (f32x4){0.f, 0.f, 0.f, 0.f};
#pragma unroll
    for (int n = 0; n < 4; ++n)
#pragma unroll
      for (int kc = 0; kc < 4; ++kc) {
        bf16x8 kf = *(const bf16x8*)(sKb + ((n * 16 + l15) * 128 + kc * 32 + quad * 8) * 2);
        sacc[n] = MFMA16(qf[kc], kf, sacc[n]);
      }

#pragma unroll
    for (int r = 0; r < 4; ++r) {
      int row = qrow0 + quad * 4 + r;
      float v[4];
      float mx = -1e30f;
#pragma unroll
      for (int n = 0; n < 4; ++n) {
        int key = kb * 64 + n * 16 + l15;
        float s = sacc[n][r] * kSc;
        s = (key > row) ? -1e30f : s;
        v[n] = s;
        mx = fmaxf(mx, s);
      }
#pragma unroll
      for (int d = 1; d < 16; d <<= 1) mx = fmaxf(mx, __shfl_xor(mx, d, 64));
      float mnew = fmaxf(mrow[r], mx);
      float alpha = exp2f(mrow[r] - mnew);
      float sum = 0.f;
#pragma unroll
      for (int n = 0; n < 4; ++n) {
        float p = exp2f(v[n] - mnew);
        sum += p;
        sP[wave][(quad * 4 + r) * 72 + n * 16 + l15] = __float2bfloat16(p);
      }
#pragma unroll
      for (int d = 1; d < 16; d <<= 1) sum += __shfl_xor(sum, d, 64);
      lrow[r] = lrow[r] * alpha + sum;
      mrow[r] = mnew;
#pragma unroll
      for (int nf = 0; nf < 8; ++nf) of[nf][r] = of[nf][r] * alpha;
    }

#pragma unroll
    for (int kc = 0; kc < 2; ++kc) {
      bf16x8 pf = *(const bf16x8*)((const char*)&sP[wave][0] + (l15 * 72 + kc * 32 + quad * 8) * 2);
#pragma unroll
      for (int nf = 0; nf < 8; ++nf) {
        bf16x8 vf = *(const bf16x8*)(sVb + ((nf * 16 + l15) * 64 + kc * 32 + quad * 8) * 2);
        of[nf] = MFMA16(pf, vf, of[nf]);
      }
    }
    __syncthreads();
  }

  float invl[4];
#pragma unroll
  for (int r = 0; r < 4; ++r) invl[r] = 1.f / lrow[r];
#pragma unroll
  for (int nf = 0; nf < 8; ++nf)
#pragma unroll
    for (int r = 0; r < 4; ++r)
      O[(size_t)(qrow0 + quad * 4 + r) * 4096 + h * 128 + nf * 16 + l15] =
          __float2bfloat16(of[nf][r] * invl[r]);
}

// ---------------------------------------------------------------------- launch
extern "C" void kernel_launch(void* const* d_in, const int* in_sizes, int n_in,
                              void* d_out, int out_size, void* d_ws, size_t ws_size,
                              hipStream_t stream) {
  const float* x = (const float*)d_in[0];
  const float* wq = (const float*)d_in[1];
  const float* wk = (const float*)d_in[2];
  const float* wv = (const float*)d_in[3];
  const float* wo = (const float*)d_in[4];
  const float* fc = (const float*)d_in[5];
  const float* fs = (const float*)d_in[6];
  float* out = (float*)d_out;

  char* w = (char*)d_ws;
  size_t off = 0;
  auto alloc = [&](size_t bytes) -> char* {
    char* p = w + off;
    off += (bytes + 255) & ~(size_t)255;
    return p;
  };
  unsigned int* gmax = (unsigned int*)alloc(1024);
  hbf16* xb = (hbf16*)alloc((size_t)2048 * 4096 * 2);
  hbf16* wbuf1 = (hbf16*)alloc((size_t)4096 * 4096 * 2);  // wq_q, later wo_q
  hbf16* wbuf2 = (hbf16*)alloc((size_t)2048 * 4096 * 2);  // [wk_q; wv_q]
  float* qf32 = (float*)alloc((size_t)2048 * 4096 * 4);   // later aliased as attn_out (bf16)
  float* kvf32 = (float*)alloc((size_t)2048 * 2048 * 4);
  hbf16* qrope = (hbf16*)alloc((size_t)2048 * 4096 * 2);
  hbf16* krope = (hbf16*)alloc((size_t)2048 * 1024 * 2);
  hbf16* vt = (hbf16*)alloc((size_t)8 * 128 * 2048 * 2);
  hbf16* attno = (hbf16*)qf32;

  init_gmax_kernel<<<1, 256, 0, stream>>>(gmax);
  quant_max_kernel<<<512, 256, 0, stream>>>(wq, gmax, 0, 512);
  quant_max_kernel<<<512, 256, 0, stream>>>(wk, gmax, 64, 128);
  quant_max_kernel<<<512, 256, 0, stream>>>(wv, gmax, 128, 128);
  quant_max_kernel<<<512, 256, 0, stream>>>(wo, gmax, 192, 512);
  quant_apply_kernel<<<2048, 256, 0, stream>>>(wq, wbuf1, gmax, 0, 4096 * 4096 / 4);
  quant_apply_kernel<<<1024, 256, 0, stream>>>(wk, wbuf2, gmax, 64, 1024 * 4096 / 4);
  quant_apply_kernel<<<1024, 256, 0, stream>>>(wv, wbuf2 + (size_t)1024 * 4096, gmax, 128,
                                               1024 * 4096 / 4);
  cvt_bf16_kernel<<<2048, 256, 0, stream>>>(x, xb, 2048 * 4096 / 4);
  gemm_bt_kernel<<<dim3(16, 32), 256, 0, stream>>>(xb, wbuf1, qf32, 4096);
  gemm_bt_kernel<<<dim3(16, 16), 256, 0, stream>>>(xb, wbuf2, kvf32, 2048);
  quant_apply_kernel<<<2048, 256, 0, stream>>>(wo, wbuf1, gmax, 192, 4096 * 4096 / 4);
  rope_kernel<<<16384, 256, 0, stream>>>(qf32, fc, fs, qrope, 11, 4096);
  rope_kernel<<<4096, 256, 0, stream>>>(kvf32, fc, fs, krope, 9, 2048);
  transpose_v_kernel<<<dim3(8, 32, 2), 256, 0, stream>>>(kvf32, vt);
  attn_kernel<<<1024, 256, 0, stream>>>(qrope, krope, vt, attno);
  gemm_bt_kernel<<<dim3(16, 32), 256, 0, stream>>>(attno, wbuf1, out, 4096);
  (void)in_sizes; (void)n_in; (void)out_size; (void)ws_size;
}

// Round 2
// 638.656 us; speedup vs baseline: 1.2898x; 1.2898x over previous
//
#include <hip/hip_runtime.h>
#include <hip/hip_bf16.h>

typedef __hip_bfloat16 hbf16;
typedef __bf16 bf16x8 __attribute__((ext_vector_type(8)));
typedef float f32x4 __attribute__((ext_vector_type(4)));

#define MFMA16(a, b, c) __builtin_amdgcn_mfma_f32_16x16x32_bf16((a), (b), (c), 0, 0, 0)

// async global->LDS, 16B per lane. LDS dest = wave-uniform base + lane*16.
#define ASYNC16(ldsaddr, gaddr)                                                        \
  __builtin_amdgcn_global_load_lds(                                                    \
      (__attribute__((address_space(1))) void*)(void*)(gaddr),                         \
      (__attribute__((address_space(3))) void*)(ldsaddr), 16, 0, 0)

// ---------------------------------------------------------------- quantization
__global__ void init_gmax_kernel(unsigned int* g) { g[threadIdx.x] = 0u; }

// one block per (group, rowsplit); 64 groups of 64 cols; all matrices have 4096 cols
__global__ void quant_max_kernel(const float* __restrict__ W, unsigned int* __restrict__ gmax,
                                 int slotBase, int rowsPerSplit) {
  const int tid = threadIdx.x;
  const int group = blockIdx.x & 63;
  const int split = blockIdx.x >> 6;
  const int c4 = (tid & 15) * 4;
  const int rs = tid >> 4;  // 0..15
  const float* base = W + (size_t)(split * rowsPerSplit) * 4096 + group * 64 + c4;
  float m = 0.f;
  for (int r = rs; r < rowsPerSplit; r += 16) {
    float4 v = *(const float4*)(base + (size_t)r * 4096);
    m = fmaxf(m, fmaxf(fmaxf(fabsf(v.x), fabsf(v.y)), fmaxf(fabsf(v.z), fabsf(v.w))));
  }
  for (int d = 1; d < 64; d <<= 1) m = fmaxf(m, __shfl_xor(m, d, 64));
  __shared__ float wm_[4];
  if ((tid & 63) == 0) wm_[tid >> 6] = m;
  __syncthreads();
  if (tid == 0) {
    m = fmaxf(fmaxf(wm_[0], wm_[1]), fmaxf(wm_[2], wm_[3]));
    atomicMax(gmax + slotBase + group, __float_as_uint(m));
  }
}

// w_q = trunc(w * 2^(7-gex)) * 2^(gex-7), exact in bf16
__global__ void quant_apply_kernel(const float* __restrict__ W, hbf16* __restrict__ Wq,
                                   const unsigned int* __restrict__ gmax, int slotBase, int n4) {
  const int stride = gridDim.x * 256;
  for (int idx = blockIdx.x * 256 + threadIdx.x; idx < n4; idx += stride) {
    int col4 = idx & 1023;     // 1024 float4 per 4096-col row
    int group = col4 >> 4;     // 16 float4 per 64-col group
    unsigned int mb = gmax[slotBase + group];
    int gex = (int)((mb >> 23) & 255) - 127;
    float s = __uint_as_float((unsigned)(134 - gex) << 23);    // 2^(7-gex)
    float inv = __uint_as_float((unsigned)(120 + gex) << 23);  // 2^(gex-7)
    float4 w = *(const float4*)(W + (size_t)idx * 4);
    hbf16 t[4];
    t[0] = __float2bfloat16(truncf(w.x * s) * inv);
    t[1] = __float2bfloat16(truncf(w.y * s) * inv);
    t[2] = __float2bfloat16(truncf(w.z * s) * inv);
    t[3] = __float2bfloat16(truncf(w.w * s) * inv);
    *(uint2*)(Wq + (size_t)idx * 4) = *(uint2*)t;
  }
}

__global__ void cvt_bf16_kernel(const float* __restrict__ X, hbf16* __restrict__ Y, int n4) {
  const int stride = gridDim.x * 256;
  for (int idx = blockIdx.x * 256 + threadIdx.x; idx < n4; idx += stride) {
    float4 v = *(const float4*)(X + (size_t)idx * 4);
    hbf16 t[4] = {__float2bfloat16(v.x), __float2bfloat16(v.y),
                  __float2bfloat16(v.z), __float2bfloat16(v.w)};
    *(uint2*)(Y + (size_t)idx * 4) = *(uint2*)t;
  }
}

// -------------------------------------------------------------------- RoPE
__global__ void rope_kernel(const float* __restrict__ In, const float* __restrict__ Cs,
                            const float* __restrict__ Sn, hbf16* __restrict__ Out,
                            int shift, int rowStride) {
  int i = blockIdx.x * 256 + threadIdx.x;
  int ppr = 1 << shift;
  if (i >= 2048 * ppr) return;
  int s = i >> shift;
  int p = i & (ppr - 1);
  int t = p & 63;
  float2 q = *(const float2*)(In + (size_t)s * rowStride + p * 2);
  float c = Cs[s * 64 + t], sn = Sn[s * 64 + t];
  hbf16 o[2] = {__float2bfloat16(q.x * c - q.y * sn), __float2bfloat16(q.x * sn + q.y * c)};
  *(unsigned int*)(Out + (size_t)s * ppr * 2 + p * 2) = *(unsigned int*)o;
}

// V [s][1024+g*128+d] (f32) -> Vt [g][d][s] (bf16)
__global__ void transpose_v_kernel(const float* __restrict__ KV, hbf16* __restrict__ Vt) {
  __shared__ float tile[64][65];
  const int g = blockIdx.x, sb = blockIdx.y, db = blockIdx.z;
  const int tid = threadIdx.x;
  const int c = tid & 63;
  for (int r = tid >> 6; r < 64; r += 4)
    tile[r][c] = KV[(size_t)(sb * 64 + r) * 2048 + 1024 + g * 128 + db * 64 + c];
  __syncthreads();
  for (int r = tid >> 6; r < 64; r += 4)
    Vt[(size_t)g * 262144 + (size_t)(db * 64 + r) * 2048 + sb * 64 + c] =
        __float2bfloat16(tile[c][r]);
}

// ------------------------------------------------------------------ GEMM C=A*Bt^T
// XOR-swizzled LDS: logical 16B chunk c of row r lives at physical chunk c^(r&7).
__global__ __launch_bounds__(256) void gemm_bt_kernel(const hbf16* __restrict__ A,
                                                      const hbf16* __restrict__ Bt,
                                                      float* __restrict__ C, int N) {
  constexpr int K = 4096;
  __shared__ __align__(16) hbf16 sA[128 * 64];
  __shared__ __align__(16) hbf16 sB[128 * 64];
  const int tid = threadIdx.x;
  const int wave = tid >> 6, lane = tid & 63;
  const int l15 = lane & 15, quad = lane >> 4;
  const int bm = blockIdx.x, bn = blockIdx.y;
  const int wm = (wave >> 1) * 64, wn = (wave & 1) * 64;

  const char* Ab = (const char*)(A + (size_t)bm * 128 * K);
  const char* Bb = (const char*)(Bt + (size_t)bn * 128 * K);
  char* sAb = (char*)sA;
  char* sBb = (char*)sB;

  f32x4 acc[4][4];
#pragma unroll
  for (int i = 0; i < 4; ++i)
#pragma unroll
    for (int n = 0; n < 4; ++n) acc[i][n] = (f32x4){0.f, 0.f, 0.f, 0.f};

  for (int kk = 0; kk < K; kk += 64) {
#pragma unroll
    for (int r = 0; r < 4; ++r) {
      int f = r * 4096 + tid * 16;
      int row = f >> 7;
      int lc = ((f >> 4) & 7) ^ (row & 7);  // logical chunk for this physical slot
      ASYNC16(sAb + f, Ab + (size_t)row * (K * 2) + kk * 2 + lc * 16);
      ASYNC16(sBb + f, Bb + (size_t)row * (K * 2) + kk * 2 + lc * 16);
    }
    __syncthreads();
#pragma unroll
    for (int kc = 0; kc < 2; ++kc) {
      bf16x8 af[4], bg[4];
#pragma unroll
      for (int i = 0; i < 4; ++i)
        af[i] = *(const bf16x8*)(sAb + (wm + i * 16 + l15) * 128 +
                                 (((kc << 2) | quad) ^ (l15 & 7)) * 16);
#pragma unroll
      for (int n = 0; n < 4; ++n)
        bg[n] = *(const bf16x8*)(sBb + (wn + n * 16 + l15) * 128 +
                                 (((kc << 2) | quad) ^ (l15 & 7)) * 16);
#pragma unroll
      for (int i = 0; i < 4; ++i)
#pragma unroll
        for (int n = 0; n < 4; ++n) acc[i][n] = MFMA16(af[i], bg[n], acc[i][n]);
    }
    __syncthreads();
  }
#pragma unroll
  for (int i = 0; i < 4; ++i) {
    int row = bm * 128 + wm + i * 16 + quad * 4;
#pragma unroll
    for (int n = 0; n < 4; ++n) {
      float* cp = C + (size_t)row * N + bn * 128 + wn + n * 16 + l15;
#pragma unroll
      for (int r = 0; r < 4; ++r) cp[(size_t)r * N] = acc[i][n][r];
    }
  }
}

// ------------------------------------------------------------- flash attention
// S^T formulation: S^T = K·Q^T (C col = qrow -> per-lane scalar softmax state),
// O^T = V^T·P^T with P^T's B-fragment built in-register via shuffles.
// Q [2048][4096] bf16, Kr [2048][1024] bf16, Vt [8][128][2048] bf16, O [2048][4096] bf16.
__global__ __launch_bounds__(256, 4) void attn_kernel(const hbf16* __restrict__ Q,
                                                      const hbf16* __restrict__ Kr,
                                                      const hbf16* __restrict__ Vt,
                                                      hbf16* __restrict__ O) {
  __shared__ __align__(16) hbf16 sK[64 * 128];  // [key][d], chunk^(key&15) swizzle
  __shared__ __align__(16) hbf16 sV[128 * 64];  // [d][key], chunk^(d&7) swizzle
  const int tid = threadIdx.x;
  const int wave = tid >> 6, lane = tid & 63;
  const int l15 = lane & 15, quad = lane >> 4;
  const int bid = blockIdx.x;
  const int h = bid >> 5;
  const int qb = (31 - (bid & 31) + 8 * (h & 3)) & 31;  // per-CU load balance scramble
  const int g = h >> 2;
  const int qrow0 = qb * 64 + wave * 16;
  const int qrow = qrow0 + l15;  // this lane's query row (S^T col)

  bf16x8 qf[4];
  {
    const hbf16* qp = Q + (size_t)qrow * 4096 + h * 128 + quad * 8;
#pragma unroll
    for (int kc = 0; kc < 4; ++kc) qf[kc] = *(const bf16x8*)(qp + kc * 32);
  }
  f32x4 of[8];
#pragma unroll
  for (int nf = 0; nf < 8; ++nf) of[nf] = (f32x4){0.f, 0.f, 0.f, 0.f};
  float m_i = -1e30f, l_i = 0.f;

  const char* Kb = (const char*)Kr + (size_t)g * 256;     // + key*2048 + d*2
  const char* Vb = (const char*)Vt + (size_t)g * 524288;  // + d*4096 + key*2
  char* sKb = (char*)sK;
  char* sVb = (char*)sV;
  const float kSc = 0.12753139668280277f;  // (1/sqrt(128)) * log2(e)

  const int nkb = qb + 1;
  for (int kb = 0; kb < nkb; ++kb) {
#pragma unroll
    for (int r = 0; r < 4; ++r) {
      int f = r * 4096 + tid * 16;
      {
        int row = f >> 8;                          // K: 64 keys x 256B
        int lc = ((f >> 4) & 15) ^ (row & 15);     // logical d-chunk
        ASYNC16(sKb + f, Kb + (size_t)(kb * 64 + row) * 2048 + lc * 16);
      }
      {
        int row = f >> 7;                          // Vt: 128 d x 128B
        int lc = ((f >> 4) & 7) ^ (row & 7);       // logical key-chunk
        ASYNC16(sVb + f, Vb + (size_t)row * 4096 + kb * 128 + lc * 16);
      }
    }
    __syncthreads();

    // S^T tiles: sacc[n] holds S^T[key = n*16 + quad*4 + r][qrow]
    f32x4 sacc[4];
#pragma unroll
    for (int n = 0; n < 4; ++n) sacc[n] = (f32x4){0.f, 0.f, 0.f, 0.f};
#pragma unroll
    for (int n = 0; n < 4; ++n)
#pragma unroll
      for (int kc = 0; kc < 4; ++kc) {
        bf16x8 kf = *(const bf16x8*)(sKb + (n * 16 + l15) * 256 +
                                     (((kc << 2) | quad) ^ l15) * 16);
        sacc[n] = MFMA16(kf, qf[kc], sacc[n]);
      }

    // online softmax: all 16 values belong to this lane's qrow
    float p[4][4];
    float mx = -1e30f;
    const int key0 = kb * 64 + quad * 4;
#pragma unroll
    for (int n = 0; n < 4; ++n)
#pragma unroll
      for (int r = 0; r < 4; ++r) {
        float s = sacc[n][r] * kSc;
        s = (key0 + n * 16 + r > qrow) ? -1e30f : s;
        p[n][r] = s;
        mx = fmaxf(mx, s);
      }
    mx = fmaxf(mx, __shfl_xor(mx, 16, 64));
    mx = fmaxf(mx, __shfl_xor(mx, 32, 64));
    float mnew = fmaxf(m_i, mx);
    float alpha = exp2f(m_i - mnew);
    m_i = mnew;
    float sum = 0.f;
#pragma unroll
    for (int n = 0; n < 4; ++n)
#pragma unroll
      for (int r = 0; r < 4; ++r) {
        p[n][r] = exp2f(p[n][r] - mnew);
        sum += p[n][r];
      }
    sum += __shfl_xor(sum, 16, 64);
    sum += __shfl_xor(sum, 32, 64);
    l_i = l_i * alpha + sum;
#pragma unroll
    for (int nf = 0; nf < 8; ++nf)
#pragma unroll
      for (int r = 0; r < 4; ++r) of[nf][r] *= alpha;

    // pack P to bf16 pairs: pk[n*2+h2] = (p[n][2h2], p[n][2h2+1])
    unsigned pk[8];
#pragma unroll
    for (int n = 0; n < 4; ++n)
#pragma unroll
      for (int h2 = 0; h2 < 2; ++h2) {
        hbf16 t2[2] = {__float2bfloat16(p[n][2 * h2]), __float2bfloat16(p[n][2 * h2 + 1])};
        pk[n * 2 + h2] = *(unsigned*)t2;
      }

    // PV: O^T += V^T · P^T ; P^T B-fragment gathered via shuffles
    const int sa = ((quad & 1) << 5) + l15;  // src lane a: quad'=(quad&1)*2
    const int sb2 = sa + 16;                 // src lane b: quad'=(quad&1)*2+1
#pragma unroll
    for (int kc = 0; kc < 2; ++kc) {
      unsigned a0 = __shfl((int)pk[kc * 4 + 0], sa, 64);
      unsigned a1 = __shfl((int)pk[kc * 4 + 1], sa, 64);
      unsigned a2 = __shfl((int)pk[kc * 4 + 2], sa, 64);
      unsigned a3 = __shfl((int)pk[kc * 4 + 3], sa, 64);
      unsigned b0 = __shfl((int)pk[kc * 4 + 0], sb2, 64);
      unsigned b1 = __shfl((int)pk[kc * 4 + 1], sb2, 64);
      unsigned b2 = __shfl((int)pk[kc * 4 + 2], sb2, 64);
      unsigned b3 = __shfl((int)pk[kc * 4 + 3], sb2, 64);
      union {
        unsigned u[4];
        bf16x8 v;
      } pf;
      pf.u[0] = (quad < 2) ? a0 : a2;
      pf.u[1] = (quad < 2) ? a1 : a3;
      pf.u[2] = (quad < 2) ? b0 : b2;
      pf.u[3] = (quad < 2) ? b1 : b3;
#pragma unroll
      for (int nf = 0; nf < 8; ++nf) {
        bf16x8 vf = *(const bf16x8*)(sVb + (nf * 16 + l15) * 128 +
                                     (((kc << 2) | quad) ^ (l15 & 7)) * 16);
        of[nf] = MFMA16(vf, pf.v, of[nf]);
      }
    }
    __syncthreads();
  }

  const float invl = 1.f / l_i;
#pragma unroll
  for (int nf = 0; nf < 8; ++nf) {
    hbf16 t4[4];
#pragma unroll
    for (int r = 0; r < 4; ++r) t4[r] = __float2bfloat16(of[nf][r] * invl);
    *(uint2*)(O + (size_t)qrow * 4096 + h * 128 + nf * 16 + quad * 4) = *(uint2*)t4;
  }
}

// ---------------------------------------------------------------------- launch
extern "C" void kernel_launch(void* const* d_in, const int* in_sizes, int n_in,
                              void* d_out, int out_size, void* d_ws, size_t ws_size,
                              hipStream_t stream) {
  const float* x = (const float*)d_in[0];
  const float* wq = (const float*)d_in[1];
  const float* wk = (const float*)d_in[2];
  const float* wv = (const float*)d_in[3];
  const float* wo = (const float*)d_in[4];
  const float* fc = (const float*)d_in[5];
  const float* fs = (const float*)d_in[6];
  float* out = (float*)d_out;

  char* w = (char*)d_ws;
  size_t off = 0;
  auto alloc = [&](size_t bytes) -> char* {
    char* p = w + off;
    off += (bytes + 255) & ~(size_t)255;
    return p;
  };
  unsigned int* gmax = (unsigned int*)alloc(1024);
  hbf16* xb = (hbf16*)alloc((size_t)2048 * 4096 * 2);
  hbf16* wbuf1 = (hbf16*)alloc((size_t)4096 * 4096 * 2);  // wq_q, later wo_q
  hbf16* wbuf2 = (hbf16*)alloc((size_t)2048 * 4096 * 2);  // [wk_q; wv_q]
  float* qf32 = (float*)alloc((size_t)2048 * 4096 * 4);   // later aliased as attn_out (bf16)
  float* kvf32 = (float*)alloc((size_t)2048 * 2048 * 4);
  hbf16* qrope = (hbf16*)alloc((size_t)2048 * 4096 * 2);
  hbf16* krope = (hbf16*)alloc((size_t)2048 * 1024 * 2);
  hbf16* vt = (hbf16*)alloc((size_t)8 * 128 * 2048 * 2);
  hbf16* attno = (hbf16*)qf32;

  init_gmax_kernel<<<1, 256, 0, stream>>>(gmax);
  quant_max_kernel<<<512, 256, 0, stream>>>(wq, gmax, 0, 512);
  quant_max_kernel<<<512, 256, 0, stream>>>(wk, gmax, 64, 128);
  quant_max_kernel<<<512, 256, 0, stream>>>(wv, gmax, 128, 128);
  quant_max_kernel<<<512, 256, 0, stream>>>(wo, gmax, 192, 512);
  quant_apply_kernel<<<2048, 256, 0, stream>>>(wq, wbuf1, gmax, 0, 4096 * 4096 / 4);
  quant_apply_kernel<<<1024, 256, 0, stream>>>(wk, wbuf2, gmax, 64, 1024 * 4096 / 4);
  quant_apply_kernel<<<1024, 256, 0, stream>>>(wv, wbuf2 + (size_t)1024 * 4096, gmax, 128,
                                               1024 * 4096 / 4);
  cvt_bf16_kernel<<<2048, 256, 0, stream>>>(x, xb, 2048 * 4096 / 4);
  gemm_bt_kernel<<<dim3(16, 32), 256, 0, stream>>>(xb, wbuf1, qf32, 4096);
  gemm_bt_kernel<<<dim3(16, 16), 256, 0, stream>>>(xb, wbuf2, kvf32, 2048);
  quant_apply_kernel<<<2048, 256, 0, stream>>>(wo, wbuf1, gmax, 192, 4096 * 4096 / 4);
  rope_kernel<<<16384, 256, 0, stream>>>(qf32, fc, fs, qrope, 11, 4096);
  rope_kernel<<<4096, 256, 0, stream>>>(kvf32, fc, fs, krope, 9, 2048);
  transpose_v_kernel<<<dim3(8, 32, 2), 256, 0, stream>>>(kvf32, vt);
  attn_kernel<<<1024, 256, 0, stream>>>(qrope, krope, vt, attno);
  gemm_bt_kernel<<<dim3(16, 32), 256, 0, stream>>>(attno, wbuf1, out, 4096);
  (void)in_sizes; (void)n_in; (void)out_size; (void)ws_size;
}

// Round 3
// 588.286 us; speedup vs baseline: 1.4002x; 1.0856x over previous
//
#include <hip/hip_runtime.h>
#include <hip/hip_bf16.h>

typedef __hip_bfloat16 hbf16;
typedef __bf16 bf16x8 __attribute__((ext_vector_type(8)));
typedef float f32x4 __attribute__((ext_vector_type(4)));

#define MFMA16(a, b, c) __builtin_amdgcn_mfma_f32_16x16x32_bf16((a), (b), (c), 0, 0, 0)

// async global->LDS, 16B per lane. LDS dest = wave-uniform base + lane*16.
#define ASYNC16(ldsaddr, gaddr)                                                        \
  __builtin_amdgcn_global_load_lds(                                                    \
      (__attribute__((address_space(1))) void*)(void*)(gaddr),                         \
      (__attribute__((address_space(3))) void*)(ldsaddr), 16, 0, 0)

static __device__ __forceinline__ float fexp2(float x) {
#if __has_builtin(__builtin_amdgcn_exp2f)
  return __builtin_amdgcn_exp2f(x);
#else
  return exp2f(x);
#endif
}

// ---------------------------------------------------------------- quantization
__global__ void init_gmax_kernel(unsigned int* g) { g[threadIdx.x] = 0u; }

// grid (512, 4): x = group(64) x split(8); y = matrix {wq,wk,wv,wo}
__global__ void quant_max_kernel(const float* __restrict__ wq, const float* __restrict__ wk,
                                 const float* __restrict__ wv, const float* __restrict__ wo,
                                 unsigned int* __restrict__ gmax) {
  const int my = blockIdx.y;
  const float* W;
  int slotBase, rowsPerSplit;
  if (my == 0) { W = wq; slotBase = 0;   rowsPerSplit = 512; }
  else if (my == 1) { W = wk; slotBase = 64;  rowsPerSplit = 128; }
  else if (my == 2) { W = wv; slotBase = 128; rowsPerSplit = 128; }
  else { W = wo; slotBase = 192; rowsPerSplit = 512; }
  const int tid = threadIdx.x;
  const int group = blockIdx.x & 63;
  const int split = blockIdx.x >> 6;
  const int c4 = (tid & 15) * 4;
  const int rs = tid >> 4;  // 0..15
  const float* base = W + (size_t)(split * rowsPerSplit) * 4096 + group * 64 + c4;
  float m = 0.f;
  for (int r = rs; r < rowsPerSplit; r += 16) {
    float4 v = *(const float4*)(base + (size_t)r * 4096);
    m = fmaxf(m, fmaxf(fmaxf(fabsf(v.x), fabsf(v.y)), fmaxf(fabsf(v.z), fabsf(v.w))));
  }
  for (int d = 1; d < 64; d <<= 1) m = fmaxf(m, __shfl_xor(m, d, 64));
  __shared__ float wm_[4];
  if ((tid & 63) == 0) wm_[tid >> 6] = m;
  __syncthreads();
  if (tid == 0) {
    m = fmaxf(fmaxf(wm_[0], wm_[1]), fmaxf(wm_[2], wm_[3]));
    atomicMax(gmax + slotBase + group, __float_as_uint(m));
  }
}

// w_q = trunc(w * 2^(7-gex)) * 2^(gex-7), exact in bf16
__device__ __forceinline__ void quant_body(const float* __restrict__ W, hbf16* __restrict__ Wq,
                                           const unsigned int* __restrict__ gmax, int slotBase,
                                           int n4) {
  const int stride = gridDim.x * 256;
  for (int idx = blockIdx.x * 256 + threadIdx.x; idx < n4; idx += stride) {
    int group = (idx & 1023) >> 4;  // 16 float4 per 64-col group, 1024 float4/row
    unsigned int mb = gmax[slotBase + group];
    int gex = (int)((mb >> 23) & 255) - 127;
    float s = __uint_as_float((unsigned)(134 - gex) << 23);    // 2^(7-gex)
    float inv = __uint_as_float((unsigned)(120 + gex) << 23);  // 2^(gex-7)
    float4 w = *(const float4*)(W + (size_t)idx * 4);
    hbf16 t[4];
    t[0] = __float2bfloat16(truncf(w.x * s) * inv);
    t[1] = __float2bfloat16(truncf(w.y * s) * inv);
    t[2] = __float2bfloat16(truncf(w.z * s) * inv);
    t[3] = __float2bfloat16(truncf(w.w * s) * inv);
    *(uint2*)(Wq + (size_t)idx * 4) = *(uint2*)t;
  }
}

// grid (2048, 3): wq -> rows 0..4095, wk -> 4096..5119, wv -> 5120..6143 of stacked buffer
__global__ void quant_apply_qkv_kernel(const float* __restrict__ wq, const float* __restrict__ wk,
                                       const float* __restrict__ wv, hbf16* __restrict__ Wq,
                                       const unsigned int* __restrict__ gmax) {
  const int my = blockIdx.y;
  if (my == 0) quant_body(wq, Wq, gmax, 0, 4096 * 4096 / 4);
  else if (my == 1) quant_body(wk, Wq + (size_t)4096 * 4096, gmax, 64, 1024 * 4096 / 4);
  else quant_body(wv, Wq + (size_t)5120 * 4096, gmax, 128, 1024 * 4096 / 4);
}

__global__ void quant_apply_kernel(const float* __restrict__ W, hbf16* __restrict__ Wq,
                                   const unsigned int* __restrict__ gmax, int slotBase, int n4) {
  quant_body(W, Wq, gmax, slotBase, n4);
}

__global__ void cvt_bf16_kernel(const float* __restrict__ X, hbf16* __restrict__ Y, int n4) {
  const int stride = gridDim.x * 256;
  for (int idx = blockIdx.x * 256 + threadIdx.x; idx < n4; idx += stride) {
    float4 v = *(const float4*)(X + (size_t)idx * 4);
    hbf16 t[4] = {__float2bfloat16(v.x), __float2bfloat16(v.y),
                  __float2bfloat16(v.z), __float2bfloat16(v.w)};
    *(uint2*)(Y + (size_t)idx * 4) = *(uint2*)t;
  }
}

// -------------------------------------------------------------------- RoPE
// scale folds softmax scaling into Q (scale = 1/sqrt(128)*log2e), 1.0 for K
__global__ void rope_kernel(const float* __restrict__ In, const float* __restrict__ Cs,
                            const float* __restrict__ Sn, hbf16* __restrict__ Out,
                            int shift, int rowStride, float scale) {
  int i = blockIdx.x * 256 + threadIdx.x;
  int ppr = 1 << shift;
  if (i >= 2048 * ppr) return;
  int s = i >> shift;
  int p = i & (ppr - 1);
  int t = p & 63;
  float2 q = *(const float2*)(In + (size_t)s * rowStride + p * 2);
  float c = Cs[s * 64 + t] * scale, sn = Sn[s * 64 + t] * scale;
  hbf16 o[2] = {__float2bfloat16(q.x * c - q.y * sn), __float2bfloat16(q.x * sn + q.y * c)};
  *(unsigned int*)(Out + (size_t)s * ppr * 2 + p * 2) = *(unsigned int*)o;
}

// V = qkv[s][5120 + g*128 + d] (f32, stride 6144) -> Vt [g][d][s] (bf16)
__global__ void transpose_v_kernel(const float* __restrict__ QKV, hbf16* __restrict__ Vt) {
  __shared__ float tile[64][65];
  const int g = blockIdx.x, sb = blockIdx.y, db = blockIdx.z;
  const int tid = threadIdx.x;
  const int c = tid & 63;
  for (int r = tid >> 6; r < 64; r += 4)
    tile[r][c] = QKV[(size_t)(sb * 64 + r) * 6144 + 5120 + g * 128 + db * 64 + c];
  __syncthreads();
  for (int r = tid >> 6; r < 64; r += 4)
    Vt[(size_t)g * 262144 + (size_t)(db * 64 + r) * 2048 + sb * 64 + c] =
        __float2bfloat16(tile[c][r]);
}

// ------------------------------------------------------------------ GEMM C=A*Bt^T
// XOR-swizzled LDS: logical 16B chunk c of row r lives at physical chunk c^(r&7).
__global__ __launch_bounds__(256) void gemm_bt_kernel(const hbf16* __restrict__ A,
                                                      const hbf16* __restrict__ Bt,
                                                      float* __restrict__ C, int N) {
  constexpr int K = 4096;
  __shared__ __align__(16) hbf16 sA[128 * 64];
  __shared__ __align__(16) hbf16 sB[128 * 64];
  const int tid = threadIdx.x;
  const int wave = tid >> 6, lane = tid & 63;
  const int l15 = lane & 15, quad = lane >> 4;
  const int bm = blockIdx.x, bn = blockIdx.y;
  const int wm = (wave >> 1) * 64, wn = (wave & 1) * 64;

  const char* Ab = (const char*)(A + (size_t)bm * 128 * K);
  const char* Bb = (const char*)(Bt + (size_t)bn * 128 * K);
  char* sAb = (char*)sA;
  char* sBb = (char*)sB;

  f32x4 acc[4][4];
#pragma unroll
  for (int i = 0; i < 4; ++i)
#pragma unroll
    for (int n = 0; n < 4; ++n) acc[i][n] = (f32x4){0.f, 0.f, 0.f, 0.f};

  for (int kk = 0; kk < K; kk += 64) {
#pragma unroll
    for (int r = 0; r < 4; ++r) {
      int f = r * 4096 + tid * 16;
      int row = f >> 7;
      int lc = ((f >> 4) & 7) ^ (row & 7);  // logical chunk for this physical slot
      ASYNC16(sAb + f, Ab + (size_t)row * (K * 2) + kk * 2 + lc * 16);
      ASYNC16(sBb + f, Bb + (size_t)row * (K * 2) + kk * 2 + lc * 16);
    }
    __syncthreads();
#pragma unroll
    for (int kc = 0; kc < 2; ++kc) {
      bf16x8 af[4], bg[4];
#pragma unroll
      for (int i = 0; i < 4; ++i)
        af[i] = *(const bf16x8*)(sAb + (wm + i * 16 + l15) * 128 +
                                 (((kc << 2) | quad) ^ (l15 & 7)) * 16);
#pragma unroll
      for (int n = 0; n < 4; ++n)
        bg[n] = *(const bf16x8*)(sBb + (wn + n * 16 + l15) * 128 +
                                 (((kc << 2) | quad) ^ (l15 & 7)) * 16);
#pragma unroll
      for (int i = 0; i < 4; ++i)
#pragma unroll
        for (int n = 0; n < 4; ++n) acc[i][n] = MFMA16(af[i], bg[n], acc[i][n]);
    }
    __syncthreads();
  }
#pragma unroll
  for (int i = 0; i < 4; ++i) {
    int row = bm * 128 + wm + i * 16 + quad * 4;
#pragma unroll
    for (int n = 0; n < 4; ++n) {
      float* cp = C + (size_t)row * N + bn * 128 + wn + n * 16 + l15;
#pragma unroll
      for (int r = 0; r < 4; ++r) cp[(size_t)r * N] = acc[i][n][r];
    }
  }
}

// ------------------------------------------------------------- flash attention
// S^T formulation: S^T = K·Q^T (C col = qrow -> per-lane scalar softmax state),
// O^T = V^T·P^T with P^T's B-fragment built in-register via shuffles.
// Softmax scale pre-folded into Q. Masking only on the diagonal K-tile.
__global__ __launch_bounds__(256, 4) void attn_kernel(const hbf16* __restrict__ Q,
                                                      const hbf16* __restrict__ Kr,
                                                      const hbf16* __restrict__ Vt,
                                                      hbf16* __restrict__ O) {
  __shared__ __align__(16) hbf16 sK[64 * 128];  // [key][d], chunk^(key&15) swizzle
  __shared__ __align__(16) hbf16 sV[128 * 64];  // [d][key], chunk^(d&7) swizzle
  const int tid = threadIdx.x;
  const int wave = tid >> 6, lane = tid & 63;
  const int l15 = lane & 15, quad = lane >> 4;
  const int bid = blockIdx.x;
  const int h = bid >> 5;
  // per-CU balance: blocks {t,t+256,t+512,t+768} land on one CU and get qb
  // offsets {0,8,16,24} -> per-CU tile sum in [52,80] vs mean 66.
  const int qb = (31 - (bid & 31) + 8 * ((bid >> 8) & 3)) & 31;
  const int g = h >> 2;
  const int qrow0 = qb * 64 + wave * 16;
  const int qrow = qrow0 + l15;  // this lane's query row (S^T col)

  bf16x8 qf[4];
  {
    const hbf16* qp = Q + (size_t)qrow * 4096 + h * 128 + quad * 8;
#pragma unroll
    for (int kc = 0; kc < 4; ++kc) qf[kc] = *(const bf16x8*)(qp + kc * 32);
  }
  f32x4 of[8];
#pragma unroll
  for (int nf = 0; nf < 8; ++nf) of[nf] = (f32x4){0.f, 0.f, 0.f, 0.f};
  float m_i = -1e30f, l_i = 0.f;

  const char* Kb = (const char*)Kr + (size_t)g * 256;     // + key*2048 + d*2
  const char* Vb = (const char*)Vt + (size_t)g * 524288;  // + d*4096 + key*2
  char* sKb = (char*)sK;
  char* sVb = (char*)sV;

  const int nkb = qb + 1;
  for (int kb = 0; kb < nkb; ++kb) {
#pragma unroll
    for (int r = 0; r < 4; ++r) {
      int f = r * 4096 + tid * 16;
      {
        int row = f >> 8;                       // K: 64 keys x 256B
        int lc = ((f >> 4) & 15) ^ (row & 15);  // logical d-chunk
        ASYNC16(sKb + f, Kb + (size_t)(kb * 64 + row) * 2048 + lc * 16);
      }
      {
        int row = f >> 7;                     // Vt: 128 d x 128B
        int lc = ((f >> 4) & 7) ^ (row & 7);  // logical key-chunk
        ASYNC16(sVb + f, Vb + (size_t)row * 4096 + kb * 128 + lc * 16);
      }
    }
    __syncthreads();

    // S^T tiles: sacc[n] holds S^T[key = n*16 + quad*4 + r][qrow]
    f32x4 sacc[4];
#pragma unroll
    for (int n = 0; n < 4; ++n) sacc[n] = (f32x4){0.f, 0.f, 0.f, 0.f};
#pragma unroll
    for (int n = 0; n < 4; ++n)
#pragma unroll
      for (int kc = 0; kc < 4; ++kc) {
        bf16x8 kf = *(const bf16x8*)(sKb + (n * 16 + l15) * 256 +
                                     (((kc << 2) | quad) ^ l15) * 16);
        sacc[n] = MFMA16(kf, qf[kc], sacc[n]);
      }

    // online softmax: all 16 values belong to this lane's qrow
    float p[4][4];
    float mx = -1e30f;
    if (kb == qb) {  // diagonal tile: causal mask (wave-uniform branch)
      const int key0 = kb * 64 + quad * 4;
#pragma unroll
      for (int n = 0; n < 4; ++n)
#pragma unroll
        for (int r = 0; r < 4; ++r) {
          float s = sacc[n][r];
          s = (key0 + n * 16 + r > qrow) ? -1e30f : s;
          p[n][r] = s;
          mx = fmaxf(mx, s);
        }
    } else {
#pragma unroll
      for (int n = 0; n < 4; ++n)
#pragma unroll
        for (int r = 0; r < 4; ++r) {
          p[n][r] = sacc[n][r];
          mx = fmaxf(mx, sacc[n][r]);
        }
    }
    mx = fmaxf(mx, __shfl_xor(mx, 16, 64));
    mx = fmaxf(mx, __shfl_xor(mx, 32, 64));
    float mnew = fmaxf(m_i, mx);
    float alpha = fexp2(m_i - mnew);
    m_i = mnew;
    float sum = 0.f;
#pragma unroll
    for (int n = 0; n < 4; ++n)
#pragma unroll
      for (int r = 0; r < 4; ++r) {
        p[n][r] = fexp2(p[n][r] - mnew);
        sum += p[n][r];
      }
    sum += __shfl_xor(sum, 16, 64);
    sum += __shfl_xor(sum, 32, 64);
    l_i = l_i * alpha + sum;
#pragma unroll
    for (int nf = 0; nf < 8; ++nf)
#pragma unroll
      for (int r = 0; r < 4; ++r) of[nf][r] *= alpha;

    // pack P to bf16 pairs: pk[n*2+h2] = (p[n][2h2], p[n][2h2+1])
    unsigned pk[8];
#pragma unroll
    for (int n = 0; n < 4; ++n)
#pragma unroll
      for (int h2 = 0; h2 < 2; ++h2) {
        hbf16 t2[2] = {__float2bfloat16(p[n][2 * h2]), __float2bfloat16(p[n][2 * h2 + 1])};
        pk[n * 2 + h2] = *(unsigned*)t2;
      }

    // PV: O^T += V^T · P^T ; P^T B-fragment gathered via shuffles
    const int sa = ((quad & 1) << 5) + l15;  // src lane a: quad'=(quad&1)*2
    const int sb2 = sa + 16;                 // src lane b: quad'=(quad&1)*2+1
#pragma unroll
    for (int kc = 0; kc < 2; ++kc) {
      unsigned a0 = __shfl((int)pk[kc * 4 + 0], sa, 64);
      unsigned a1 = __shfl((int)pk[kc * 4 + 1], sa, 64);
      unsigned a2 = __shfl((int)pk[kc * 4 + 2], sa, 64);
      unsigned a3 = __shfl((int)pk[kc * 4 + 3], sa, 64);
      unsigned b0 = __shfl((int)pk[kc * 4 + 0], sb2, 64);
      unsigned b1 = __shfl((int)pk[kc * 4 + 1], sb2, 64);
      unsigned b2 = __shfl((int)pk[kc * 4 + 2], sb2, 64);
      unsigned b3 = __shfl((int)pk[kc * 4 + 3], sb2, 64);
      union {
        unsigned u[4];
        bf16x8 v;
      } pf;
      pf.u[0] = (quad < 2) ? a0 : a2;
      pf.u[1] = (quad < 2) ? a1 : a3;
      pf.u[2] = (quad < 2) ? b0 : b2;
      pf.u[3] = (quad < 2) ? b1 : b3;
#pragma unroll
      for (int nf = 0; nf < 8; ++nf) {
        bf16x8 vf = *(const bf16x8*)(sVb + (nf * 16 + l15) * 128 +
                                     (((kc << 2) | quad) ^ (l15 & 7)) * 16);
        of[nf] = MFMA16(vf, pf.v, of[nf]);
      }
    }
    __syncthreads();
  }

  const float invl = 1.f / l_i;
#pragma unroll
  for (int nf = 0; nf < 8; ++nf) {
    hbf16 t4[4];
#pragma unroll
    for (int r = 0; r < 4; ++r) t4[r] = __float2bfloat16(of[nf][r] * invl);
    *(uint2*)(O + (size_t)qrow * 4096 + h * 128 + nf * 16 + quad * 4) = *(uint2*)t4;
  }
}

// ---------------------------------------------------------------------- launch
extern "C" void kernel_launch(void* const* d_in, const int* in_sizes, int n_in,
                              void* d_out, int out_size, void* d_ws, size_t ws_size,
                              hipStream_t stream) {
  const float* x = (const float*)d_in[0];
  const float* wq = (const float*)d_in[1];
  const float* wk = (const float*)d_in[2];
  const float* wv = (const float*)d_in[3];
  const float* wo = (const float*)d_in[4];
  const float* fc = (const float*)d_in[5];
  const float* fs = (const float*)d_in[6];
  float* out = (float*)d_out;

  char* w = (char*)d_ws;
  size_t off = 0;
  auto alloc = [&](size_t bytes) -> char* {
    char* p = w + off;
    off += (bytes + 255) & ~(size_t)255;
    return p;
  };
  unsigned int* gmax = (unsigned int*)alloc(1024);
  hbf16* xb = (hbf16*)alloc((size_t)2048 * 4096 * 2);
  hbf16* wqkv = (hbf16*)alloc((size_t)6144 * 4096 * 2);  // stacked wq_q/wk_q/wv_q; later wo_q
  float* qkv = (float*)alloc((size_t)2048 * 6144 * 4);   // fused proj out; later attn_out (bf16)
  hbf16* qrope = (hbf16*)alloc((size_t)2048 * 4096 * 2);
  hbf16* krope = (hbf16*)alloc((size_t)2048 * 1024 * 2);
  hbf16* vt = (hbf16*)alloc((size_t)8 * 128 * 2048 * 2);
  hbf16* woq = wqkv;             // reused after QKV GEMM consumes wqkv
  hbf16* attno = (hbf16*)qkv;    // reused after rope/transpose consume qkv

  const float kSc = 0.12753139668280277f;  // (1/sqrt(128)) * log2(e)

  init_gmax_kernel<<<1, 256, 0, stream>>>(gmax);
  quant_max_kernel<<<dim3(512, 4), 256, 0, stream>>>(wq, wk, wv, wo, gmax);
  quant_apply_qkv_kernel<<<dim3(2048, 3), 256, 0, stream>>>(wq, wk, wv, wqkv, gmax);
  cvt_bf16_kernel<<<2048, 256, 0, stream>>>(x, xb, 2048 * 4096 / 4);
  gemm_bt_kernel<<<dim3(16, 48), 256, 0, stream>>>(xb, wqkv, qkv, 6144);
  quant_apply_kernel<<<2048, 256, 0, stream>>>(wo, woq, gmax, 192, 4096 * 4096 / 4);
  rope_kernel<<<16384, 256, 0, stream>>>(qkv, fc, fs, qrope, 11, 6144, kSc);
  rope_kernel<<<4096, 256, 0, stream>>>(qkv + 4096, fc, fs, krope, 9, 6144, 1.0f);
  transpose_v_kernel<<<dim3(8, 32, 2), 256, 0, stream>>>(qkv, vt);
  attn_kernel<<<1024, 256, 0, stream>>>(qrope, krope, vt, attno);
  gemm_bt_kernel<<<dim3(16, 32), 256, 0, stream>>>(attno, woq, out, 4096);
  (void)in_sizes; (void)n_in; (void)out_size; (void)ws_size;
}

// Round 4
// 571.360 us; speedup vs baseline: 1.4417x; 1.0296x over previous
//
#include <hip/hip_runtime.h>
#include <hip/hip_bf16.h>

typedef __hip_bfloat16 hbf16;
typedef __bf16 bf16x8 __attribute__((ext_vector_type(8)));
typedef float f32x4 __attribute__((ext_vector_type(4)));

#define MFMA16(a, b, c) __builtin_amdgcn_mfma_f32_16x16x32_bf16((a), (b), (c), 0, 0, 0)

// async global->LDS, 16B per lane. LDS dest = wave-uniform base + lane*16.
#define ASYNC16(ldsaddr, gaddr)                                                        \
  __builtin_amdgcn_global_load_lds(                                                    \
      (__attribute__((address_space(1))) void*)(void*)(gaddr),                         \
      (__attribute__((address_space(3))) void*)(ldsaddr), 16, 0, 0)

static __device__ __forceinline__ float fexp2(float x) {
#if __has_builtin(__builtin_amdgcn_exp2f)
  return __builtin_amdgcn_exp2f(x);
#else
  return exp2f(x);
#endif
}

// ---------------------------------------------------------------- quantization
// grid (512, 4): x = group(64) x split(8); y = matrix {wq,wk,wv,wo}.
// Each block writes its own (slot,split) cell -> no init, no atomics.
__global__ void quant_max_kernel(const float* __restrict__ wq, const float* __restrict__ wk,
                                 const float* __restrict__ wv, const float* __restrict__ wo,
                                 unsigned int* __restrict__ gmaxs) {
  const int my = blockIdx.y;
  const float* W;
  int slotBase, rowsPerSplit;
  if (my == 0) { W = wq; slotBase = 0;   rowsPerSplit = 512; }
  else if (my == 1) { W = wk; slotBase = 64;  rowsPerSplit = 128; }
  else if (my == 2) { W = wv; slotBase = 128; rowsPerSplit = 128; }
  else { W = wo; slotBase = 192; rowsPerSplit = 512; }
  const int tid = threadIdx.x;
  const int group = blockIdx.x & 63;
  const int split = blockIdx.x >> 6;
  const int c4 = (tid & 15) * 4;
  const int rs = tid >> 4;  // 0..15
  const float* base = W + (size_t)(split * rowsPerSplit) * 4096 + group * 64 + c4;
  float m = 0.f;
  for (int r = rs; r < rowsPerSplit; r += 16) {
    float4 v = *(const float4*)(base + (size_t)r * 4096);
    m = fmaxf(m, fmaxf(fmaxf(fabsf(v.x), fabsf(v.y)), fmaxf(fabsf(v.z), fabsf(v.w))));
  }
  for (int d = 1; d < 64; d <<= 1) m = fmaxf(m, __shfl_xor(m, d, 64));
  __shared__ float wm_[4];
  if ((tid & 63) == 0) wm_[tid >> 6] = m;
  __syncthreads();
  if (tid == 0) {
    m = fmaxf(fmaxf(wm_[0], wm_[1]), fmaxf(wm_[2], wm_[3]));
    gmaxs[(slotBase + group) * 8 + split] = __float_as_uint(m);
  }
}

// w_q = trunc(w * 2^(7-gex)) * 2^(gex-7), exact in bf16.
// blockbase/stride passed explicitly so this can be embedded in fused dispatches.
// Requires stride % 1024 == 0 (group invariant across iterations).
__device__ __forceinline__ void quant_body(const float* __restrict__ W, hbf16* __restrict__ Wq,
                                           const unsigned int* __restrict__ gmaxs, int slotBase,
                                           int n4, int block0, int nblocks) {
  const int stride = nblocks * 256;
  const int idx0 = block0 * 256 + (int)threadIdx.x;
  if (idx0 >= n4) return;
  const int slot = slotBase + ((idx0 & 1023) >> 4);
  unsigned int mb = 0;
#pragma unroll
  for (int sp = 0; sp < 8; ++sp) mb = max(mb, gmaxs[slot * 8 + sp]);
  int gex = (int)((mb >> 23) & 255) - 127;
  float s = __uint_as_float((unsigned)(134 - gex) << 23);    // 2^(7-gex)
  float inv = __uint_as_float((unsigned)(120 + gex) << 23);  // 2^(gex-7)
  for (int idx = idx0; idx < n4; idx += stride) {
    float4 w = *(const float4*)(W + (size_t)idx * 4);
    hbf16 t[4];
    t[0] = __float2bfloat16(truncf(w.x * s) * inv);
    t[1] = __float2bfloat16(truncf(w.y * s) * inv);
    t[2] = __float2bfloat16(truncf(w.z * s) * inv);
    t[3] = __float2bfloat16(truncf(w.w * s) * inv);
    *(uint2*)(Wq + (size_t)idx * 4) = *(uint2*)t;
  }
}

// grid (2048, 4): y=0 wq, y=1 wk, y=2 wv (into stacked wqkv), y=3 x->bf16
__global__ void prep_kernel(const float* __restrict__ wq, const float* __restrict__ wk,
                            const float* __restrict__ wv, const float* __restrict__ x,
                            hbf16* __restrict__ Wqkv, hbf16* __restrict__ xb,
                            const unsigned int* __restrict__ gmaxs) {
  const int my = blockIdx.y;
  if (my == 0) {
    quant_body(wq, Wqkv, gmaxs, 0, 4096 * 4096 / 4, blockIdx.x, gridDim.x);
  } else if (my == 1) {
    quant_body(wk, Wqkv + (size_t)4096 * 4096, gmaxs, 64, 1024 * 4096 / 4, blockIdx.x, gridDim.x);
  } else if (my == 2) {
    quant_body(wv, Wqkv + (size_t)5120 * 4096, gmaxs, 128, 1024 * 4096 / 4, blockIdx.x, gridDim.x);
  } else {
    const int stride = gridDim.x * 256;
    for (int idx = blockIdx.x * 256 + threadIdx.x; idx < 2048 * 4096 / 4; idx += stride) {
      float4 v = *(const float4*)(x + (size_t)idx * 4);
      hbf16 t[4] = {__float2bfloat16(v.x), __float2bfloat16(v.y),
                    __float2bfloat16(v.z), __float2bfloat16(v.w)};
      *(uint2*)(xb + (size_t)idx * 4) = *(uint2*)t;
    }
  }
}

// --------------------------------------------- post-QKV fused dispatch
// blocks [0,2048): wo quant; [2048,18432): rope Q; [18432,22528): rope K;
// [22528,23040): V transpose.  All depend only on the QKV GEMM.
__global__ void postproc_kernel(const float* __restrict__ wo, hbf16* __restrict__ woq,
                                const unsigned int* __restrict__ gmaxs,
                                const float* __restrict__ qkv, const float* __restrict__ Cs,
                                const float* __restrict__ Sn, hbf16* __restrict__ qrope,
                                hbf16* __restrict__ krope, hbf16* __restrict__ Vt, float qscale) {
  __shared__ float tile[64][65];
  const int bid = blockIdx.x;
  const int tid = threadIdx.x;
  if (bid < 2048) {
    quant_body(wo, woq, gmaxs, 192, 4096 * 4096 / 4, bid, 2048);
  } else if (bid < 18432) {
    // rope Q: 2048 pairs/row, stride 6144, scale folded
    int i = (bid - 2048) * 256 + tid;
    int s = i >> 11, p = i & 2047, t = p & 63;
    float2 q = *(const float2*)(qkv + (size_t)s * 6144 + p * 2);
    float c = Cs[s * 64 + t] * qscale, sn = Sn[s * 64 + t] * qscale;
    hbf16 o[2] = {__float2bfloat16(q.x * c - q.y * sn), __float2bfloat16(q.x * sn + q.y * c)};
    *(unsigned int*)(qrope + (size_t)s * 4096 + p * 2) = *(unsigned int*)o;
  } else if (bid < 22528) {
    // rope K: 512 pairs/row at col offset 4096
    int i = (bid - 18432) * 256 + tid;
    int s = i >> 9, p = i & 511, t = p & 63;
    float2 q = *(const float2*)(qkv + (size_t)s * 6144 + 4096 + p * 2);
    float c = Cs[s * 64 + t], sn = Sn[s * 64 + t];
    hbf16 o[2] = {__float2bfloat16(q.x * c - q.y * sn), __float2bfloat16(q.x * sn + q.y * c)};
    *(unsigned int*)(krope + (size_t)s * 1024 + p * 2) = *(unsigned int*)o;
  } else {
    // V transpose: qkv[s][5120+g*128+d] -> Vt[g][d][s]
    int id = bid - 22528;
    int g = id & 7, sb = (id >> 3) & 31, db = id >> 8;
    int c = tid & 63;
    for (int r = tid >> 6; r < 64; r += 4)
      tile[r][c] = qkv[(size_t)(sb * 64 + r) * 6144 + 5120 + g * 128 + db * 64 + c];
    __syncthreads();
    for (int r = tid >> 6; r < 64; r += 4)
      Vt[(size_t)g * 262144 + (size_t)(db * 64 + r) * 2048 + sb * 64 + c] =
          __float2bfloat16(tile[c][r]);
  }
}

// ------------------------------------------------------------------ GEMM C=A*Bt^T
// 128 x BN tile, BK=64, XOR-swizzled LDS (chunk c of row r at physical c^(r&7)).
// BN in {64, 96, 128}; waves 2x2, wave tile 64 x BN/2.
template <int BN>
__global__ __launch_bounds__(256) void gemm_bt_kernel(const hbf16* __restrict__ A,
                                                      const hbf16* __restrict__ Bt,
                                                      float* __restrict__ C, int N) {
  constexpr int K = 4096;
  constexpr int NF = BN / 32;  // B-frags per wave
  __shared__ __align__(16) hbf16 sA[128 * 64];
  __shared__ __align__(16) hbf16 sB[BN * 64];
  const int tid = threadIdx.x;
  const int wave = tid >> 6, lane = tid & 63;
  const int l15 = lane & 15, quad = lane >> 4;
  const int bm = blockIdx.x, bn = blockIdx.y;
  const int wm = (wave >> 1) * 64, wn = (wave & 1) * (BN / 2);

  const char* Ab = (const char*)(A + (size_t)bm * 128 * K);
  const char* Bb = (const char*)(Bt + (size_t)bn * BN * K);
  char* sAb = (char*)sA;
  char* sBb = (char*)sB;

  f32x4 acc[4][NF];
#pragma unroll
  for (int i = 0; i < 4; ++i)
#pragma unroll
    for (int n = 0; n < NF; ++n) acc[i][n] = (f32x4){0.f, 0.f, 0.f, 0.f};

  for (int kk = 0; kk < K; kk += 64) {
#pragma unroll
    for (int r = 0; r < 4; ++r) {
      int f = r * 4096 + tid * 16;
      int row = f >> 7;
      int lc = ((f >> 4) & 7) ^ (row & 7);
      ASYNC16(sAb + f, Ab + (size_t)row * (K * 2) + kk * 2 + lc * 16);
    }
#pragma unroll
    for (int r = 0; r < NF; ++r) {
      int f = r * 4096 + tid * 16;
      int row = f >> 7;
      int lc = ((f >> 4) & 7) ^ (row & 7);
      ASYNC16(sBb + f, Bb + (size_t)row * (K * 2) + kk * 2 + lc * 16);
    }
    __syncthreads();
#pragma unroll
    for (int kc = 0; kc < 2; ++kc) {
      bf16x8 af[4], bg[NF];
#pragma unroll
      for (int i = 0; i < 4; ++i)
        af[i] = *(const bf16x8*)(sAb + (wm + i * 16 + l15) * 128 +
                                 (((kc << 2) | quad) ^ (l15 & 7)) * 16);
#pragma unroll
      for (int n = 0; n < NF; ++n)
        bg[n] = *(const bf16x8*)(sBb + (wn + n * 16 + l15) * 128 +
                                 (((kc << 2) | quad) ^ (l15 & 7)) * 16);
#pragma unroll
      for (int i = 0; i < 4; ++i)
#pragma unroll
        for (int n = 0; n < NF; ++n) acc[i][n] = MFMA16(af[i], bg[n], acc[i][n]);
    }
    __syncthreads();
  }
#pragma unroll
  for (int i = 0; i < 4; ++i) {
    int row = bm * 128 + wm + i * 16 + quad * 4;
#pragma unroll
    for (int n = 0; n < NF; ++n) {
      float* cp = C + (size_t)row * N + bn * BN + wn + n * 16 + l15;
#pragma unroll
      for (int r = 0; r < 4; ++r) cp[(size_t)r * N] = acc[i][n][r];
    }
  }
}

// ------------------------------------------------------------- flash attention
// S^T formulation: S^T = K·Q^T (C col = qrow -> per-lane scalar softmax state),
// O^T = V^T·P^T with P^T's B-fragment built in-register via shuffles.
// Softmax scale pre-folded into Q. Masking only on the diagonal K-tile.
__global__ __launch_bounds__(256, 4) void attn_kernel(const hbf16* __restrict__ Q,
                                                      const hbf16* __restrict__ Kr,
                                                      const hbf16* __restrict__ Vt,
                                                      hbf16* __restrict__ O) {
  __shared__ __align__(16) hbf16 sK[64 * 128];  // [key][d], chunk^(key&15) swizzle
  __shared__ __align__(16) hbf16 sV[128 * 64];  // [d][key], chunk^(d&7) swizzle
  const int tid = threadIdx.x;
  const int wave = tid >> 6, lane = tid & 63;
  const int l15 = lane & 15, quad = lane >> 4;
  const int bid = blockIdx.x;
  const int h = bid >> 5;
  // per-CU balance: blocks {t,t+256,t+512,t+768} land on one CU and get qb
  // offsets {0,8,16,24} -> per-CU tile sum in [52,80] vs mean 66.
  const int qb = (31 - (bid & 31) + 8 * ((bid >> 8) & 3)) & 31;
  const int g = h >> 2;
  const int qrow0 = qb * 64 + wave * 16;
  const int qrow = qrow0 + l15;  // this lane's query row (S^T col)

  bf16x8 qf[4];
  {
    const hbf16* qp = Q + (size_t)qrow * 4096 + h * 128 + quad * 8;
#pragma unroll
    for (int kc = 0; kc < 4; ++kc) qf[kc] = *(const bf16x8*)(qp + kc * 32);
  }
  f32x4 of[8];
#pragma unroll
  for (int nf = 0; nf < 8; ++nf) of[nf] = (f32x4){0.f, 0.f, 0.f, 0.f};
  float m_i = -1e30f, l_i = 0.f;

  const char* Kb = (const char*)Kr + (size_t)g * 256;     // + key*2048 + d*2
  const char* Vb = (const char*)Vt + (size_t)g * 524288;  // + d*4096 + key*2
  char* sKb = (char*)sK;
  char* sVb = (char*)sV;

  const int nkb = qb + 1;
  for (int kb = 0; kb < nkb; ++kb) {
#pragma unroll
    for (int r = 0; r < 4; ++r) {
      int f = r * 4096 + tid * 16;
      {
        int row = f >> 8;                       // K: 64 keys x 256B
        int lc = ((f >> 4) & 15) ^ (row & 15);  // logical d-chunk
        ASYNC16(sKb + f, Kb + (size_t)(kb * 64 + row) * 2048 + lc * 16);
      }
      {
        int row = f >> 7;                     // Vt: 128 d x 128B
        int lc = ((f >> 4) & 7) ^ (row & 7);  // logical key-chunk
        ASYNC16(sVb + f, Vb + (size_t)row * 4096 + kb * 128 + lc * 16);
      }
    }
    __syncthreads();

    // S^T tiles: sacc[n] holds S^T[key = n*16 + quad*4 + r][qrow]
    f32x4 sacc[4];
#pragma unroll
    for (int n = 0; n < 4; ++n) sacc[n] = (f32x4){0.f, 0.f, 0.f, 0.f};
#pragma unroll
    for (int n = 0; n < 4; ++n)
#pragma unroll
      for (int kc = 0; kc < 4; ++kc) {
        bf16x8 kf = *(const bf16x8*)(sKb + (n * 16 + l15) * 256 +
                                     (((kc << 2) | quad) ^ l15) * 16);
        sacc[n] = MFMA16(kf, qf[kc], sacc[n]);
      }

    // online softmax: all 16 values belong to this lane's qrow
    float p[4][4];
    float mx = -1e30f;
    if (kb == qb) {  // diagonal tile: causal mask (wave-uniform branch)
      const int key0 = kb * 64 + quad * 4;
#pragma unroll
      for (int n = 0; n < 4; ++n)
#pragma unroll
        for (int r = 0; r < 4; ++r) {
          float s = sacc[n][r];
          s = (key0 + n * 16 + r > qrow) ? -1e30f : s;
          p[n][r] = s;
          mx = fmaxf(mx, s);
        }
    } else {
#pragma unroll
      for (int n = 0; n < 4; ++n)
#pragma unroll
        for (int r = 0; r < 4; ++r) {
          p[n][r] = sacc[n][r];
          mx = fmaxf(mx, sacc[n][r]);
        }
    }
    mx = fmaxf(mx, __shfl_xor(mx, 16, 64));
    mx = fmaxf(mx, __shfl_xor(mx, 32, 64));
    float mnew = fmaxf(m_i, mx);
    float alpha = fexp2(m_i - mnew);
    m_i = mnew;
    float sum = 0.f;
#pragma unroll
    for (int n = 0; n < 4; ++n)
#pragma unroll
      for (int r = 0; r < 4; ++r) {
        p[n][r] = fexp2(p[n][r] - mnew);
        sum += p[n][r];
      }
    sum += __shfl_xor(sum, 16, 64);
    sum += __shfl_xor(sum, 32, 64);
    l_i = l_i * alpha + sum;
#pragma unroll
    for (int nf = 0; nf < 8; ++nf)
#pragma unroll
      for (int r = 0; r < 4; ++r) of[nf][r] *= alpha;

    // pack P to bf16 pairs: pk[n*2+h2] = (p[n][2h2], p[n][2h2+1])
    unsigned pk[8];
#pragma unroll
    for (int n = 0; n < 4; ++n)
#pragma unroll
      for (int h2 = 0; h2 < 2; ++h2) {
        hbf16 t2[2] = {__float2bfloat16(p[n][2 * h2]), __float2bfloat16(p[n][2 * h2 + 1])};
        pk[n * 2 + h2] = *(unsigned*)t2;
      }

    // PV: O^T += V^T · P^T ; P^T B-fragment gathered via shuffles
    const int sa = ((quad & 1) << 5) + l15;  // src lane a: quad'=(quad&1)*2
    const int sb2 = sa + 16;                 // src lane b: quad'=(quad&1)*2+1
#pragma unroll
    for (int kc = 0; kc < 2; ++kc) {
      unsigned a0 = __shfl((int)pk[kc * 4 + 0], sa, 64);
      unsigned a1 = __shfl((int)pk[kc * 4 + 1], sa, 64);
      unsigned a2 = __shfl((int)pk[kc * 4 + 2], sa, 64);
      unsigned a3 = __shfl((int)pk[kc * 4 + 3], sa, 64);
      unsigned b0 = __shfl((int)pk[kc * 4 + 0], sb2, 64);
      unsigned b1 = __shfl((int)pk[kc * 4 + 1], sb2, 64);
      unsigned b2 = __shfl((int)pk[kc * 4 + 2], sb2, 64);
      unsigned b3 = __shfl((int)pk[kc * 4 + 3], sb2, 64);
      union {
        unsigned u[4];
        bf16x8 v;
      } pf;
      pf.u[0] = (quad < 2) ? a0 : a2;
      pf.u[1] = (quad < 2) ? a1 : a3;
      pf.u[2] = (quad < 2) ? b0 : b2;
      pf.u[3] = (quad < 2) ? b1 : b3;
#pragma unroll
      for (int nf = 0; nf < 8; ++nf) {
        bf16x8 vf = *(const bf16x8*)(sVb + (nf * 16 + l15) * 128 +
                                     (((kc << 2) | quad) ^ (l15 & 7)) * 16);
        of[nf] = MFMA16(vf, pf.v, of[nf]);
      }
    }
    __syncthreads();
  }

  const float invl = 1.f / l_i;
#pragma unroll
  for (int nf = 0; nf < 8; ++nf) {
    hbf16 t4[4];
#pragma unroll
    for (int r = 0; r < 4; ++r) t4[r] = __float2bfloat16(of[nf][r] * invl);
    *(uint2*)(O + (size_t)qrow * 4096 + h * 128 + nf * 16 + quad * 4) = *(uint2*)t4;
  }
}

// ---------------------------------------------------------------------- launch
extern "C" void kernel_launch(void* const* d_in, const int* in_sizes, int n_in,
                              void* d_out, int out_size, void* d_ws, size_t ws_size,
                              hipStream_t stream) {
  const float* x = (const float*)d_in[0];
  const float* wq = (const float*)d_in[1];
  const float* wk = (const float*)d_in[2];
  const float* wv = (const float*)d_in[3];
  const float* wo = (const float*)d_in[4];
  const float* fc = (const float*)d_in[5];
  const float* fs = (const float*)d_in[6];
  float* out = (float*)d_out;

  char* w = (char*)d_ws;
  size_t off = 0;
  auto alloc = [&](size_t bytes) -> char* {
    char* p = w + off;
    off += (bytes + 255) & ~(size_t)255;
    return p;
  };
  unsigned int* gmaxs = (unsigned int*)alloc(256 * 8 * 4);
  hbf16* xb = (hbf16*)alloc((size_t)2048 * 4096 * 2);
  hbf16* wqkv = (hbf16*)alloc((size_t)6144 * 4096 * 2);  // stacked wq_q/wk_q/wv_q; later wo_q
  float* qkv = (float*)alloc((size_t)2048 * 6144 * 4);   // fused proj out; later attn_out (bf16)
  hbf16* qrope = (hbf16*)alloc((size_t)2048 * 4096 * 2);
  hbf16* krope = (hbf16*)alloc((size_t)2048 * 1024 * 2);
  hbf16* vt = (hbf16*)alloc((size_t)8 * 128 * 2048 * 2);
  hbf16* woq = wqkv;           // reused after QKV GEMM consumes wqkv
  hbf16* attno = (hbf16*)qkv;  // reused after rope/transpose consume qkv

  const float kSc = 0.12753139668280277f;  // (1/sqrt(128)) * log2(e)

  quant_max_kernel<<<dim3(512, 4), 256, 0, stream>>>(wq, wk, wv, wo, gmaxs);
  prep_kernel<<<dim3(2048, 4), 256, 0, stream>>>(wq, wk, wv, x, wqkv, xb, gmaxs);
  gemm_bt_kernel<96><<<dim3(16, 64), 256, 0, stream>>>(xb, wqkv, qkv, 6144);
  postproc_kernel<<<23040, 256, 0, stream>>>(wo, woq, gmaxs, qkv, fc, fs, qrope, krope, vt, kSc);
  attn_kernel<<<1024, 256, 0, stream>>>(qrope, krope, vt, attno);
  gemm_bt_kernel<64><<<dim3(16, 64), 256, 0, stream>>>(attno, woq, out, 4096);
  (void)in_sizes; (void)n_in; (void)out_size; (void)ws_size;
}